// Round 1
// baseline (928.108 us; speedup 1.0000x reference)
//
#include <hip/hip_runtime.h>

typedef unsigned short u16;
typedef __bf16 bf16x8 __attribute__((ext_vector_type(8)));
typedef float  f32x4  __attribute__((ext_vector_type(4)));

__device__ __forceinline__ float b2f(u16 u) {
    unsigned int v = ((unsigned int)u) << 16;
    return __builtin_bit_cast(float, v);
}
__device__ __forceinline__ u16 f2b(float f) {
    unsigned int v = __builtin_bit_cast(unsigned int, f);
    v += 0x7fffu + ((v >> 16) & 1u);
    return (u16)(v >> 16);
}

// async global->LDS, 16B per lane; LDS dest = wave-uniform base + lane*16
#define GLD16(gp, lp) __builtin_amdgcn_global_load_lds( \
    (const __attribute__((address_space(1))) void*)(gp), \
    (__attribute__((address_space(3))) void*)(lp), 16, 0, 0)

// ---------------------------------------------------------------- prep kernels

__global__ __launch_bounds__(256) void convert_x(const float* __restrict__ x,
                                                 u16* __restrict__ xb) {
    size_t i = ((size_t)blockIdx.x * 256 + threadIdx.x) * 8;
    float4 v0 = *(const float4*)(x + i);
    float4 v1 = *(const float4*)(x + i + 4);
    ushort4 o0, o1;
    o0.x = f2b(v0.x); o0.y = f2b(v0.y); o0.z = f2b(v0.z); o0.w = f2b(v0.w);
    o1.x = f2b(v1.x); o1.y = f2b(v1.y); o1.z = f2b(v1.z); o1.w = f2b(v1.w);
    *(ushort4*)(xb + i)     = o0;
    *(ushort4*)(xb + i + 4) = o1;
}

// Wt[n][k] = bf16(W[k][n]), 1024x1024, LDS-tiled transpose
__global__ __launch_bounds__(256) void transpose_w(const float* __restrict__ W,
                                                   u16* __restrict__ Wt) {
    __shared__ float tile[64][65];
    int kt = (blockIdx.x & 15) * 64;
    int nt = (blockIdx.x >> 4) * 64;
    int tid = threadIdx.x;
    int r = tid >> 4, c4 = (tid & 15) * 4;
    #pragma unroll
    for (int p = 0; p < 4; ++p) {
        int k = kt + p * 16 + r;
        float4 v = *(const float4*)(W + (size_t)k * 1024 + nt + c4);
        tile[c4 + 0][p * 16 + r] = v.x;
        tile[c4 + 1][p * 16 + r] = v.y;
        tile[c4 + 2][p * 16 + r] = v.z;
        tile[c4 + 3][p * 16 + r] = v.w;
    }
    __syncthreads();
    #pragma unroll
    for (int p = 0; p < 4; ++p) {
        int nl = p * 16 + r;
        ushort4 o;
        o.x = f2b(tile[nl][c4 + 0]); o.y = f2b(tile[nl][c4 + 1]);
        o.z = f2b(tile[nl][c4 + 2]); o.w = f2b(tile[nl][c4 + 3]);
        *(ushort4*)(Wt + (size_t)(nt + nl) * 1024 + kt + c4) = o;
    }
}

// Wut[b][n][k] = bf16(Wu[k][n] * p_av[b][k])  (fold p_av into per-batch B)
__global__ __launch_bounds__(256) void wu_prime(const float* __restrict__ Wu,
                                                const float* __restrict__ p_av,
                                                u16* __restrict__ Wut) {
    __shared__ float tile[64][65];
    int kt = (blockIdx.x & 15) * 64;
    int nt = (blockIdx.x >> 4) * 64;
    int tid = threadIdx.x;
    int r = tid >> 4, c4 = (tid & 15) * 4;
    #pragma unroll
    for (int p = 0; p < 4; ++p) {
        int k = kt + p * 16 + r;
        float4 v = *(const float4*)(Wu + (size_t)k * 1024 + nt + c4);
        tile[c4 + 0][p * 16 + r] = v.x;
        tile[c4 + 1][p * 16 + r] = v.y;
        tile[c4 + 2][p * 16 + r] = v.z;
        tile[c4 + 3][p * 16 + r] = v.w;
    }
    __syncthreads();
    for (int b = 0; b < 8; ++b) {
        float4 pv = *(const float4*)(p_av + (size_t)b * 1024 + kt + c4);
        #pragma unroll
        for (int p = 0; p < 4; ++p) {
            int nl = p * 16 + r;
            ushort4 o;
            o.x = f2b(tile[nl][c4 + 0] * pv.x);
            o.y = f2b(tile[nl][c4 + 1] * pv.y);
            o.z = f2b(tile[nl][c4 + 2] * pv.z);
            o.w = f2b(tile[nl][c4 + 3] * pv.w);
            *(ushort4*)(Wut + ((size_t)b * 1024 + nt + nl) * 1024 + kt + c4) = o;
        }
    }
}

__global__ __launch_bounds__(256) void wat_prep(const float* __restrict__ Wa,
                                                u16* __restrict__ Wat) {
    int idx = blockIdx.x * 256 + threadIdx.x;   // 16384 = 16 h * 1024 k
    int h = idx >> 10, k = idx & 1023;
    Wat[idx] = f2b(Wa[(k << 4) + h]);
}

// Wbt[b][h][k] = bf16(Wb[k][h] * q_av[b][k])
__global__ __launch_bounds__(256) void wbt_prep(const float* __restrict__ Wb,
                                                const float* __restrict__ q_av,
                                                u16* __restrict__ Wbt) {
    int idx = blockIdx.x * 256 + threadIdx.x;   // 131072
    int b = idx >> 14, rem = idx & 16383;
    int h = rem >> 10, k = rem & 1023;
    Wbt[idx] = f2b(Wb[(k << 4) + h] * q_av[(b << 10) + k]);
}

__global__ __launch_bounds__(256) void bias_concat(const float* __restrict__ bq,
                                                   const float* __restrict__ bk,
                                                   const float* __restrict__ bv,
                                                   float* __restrict__ outb) {
    int i = blockIdx.x * 256 + threadIdx.x;     // 3072
    outb[i] = (i < 1024) ? bq[i] : (i < 2048 ? bk[i - 1024] : bv[i - 2048]);
}

// ---------------------------------------------------------------- main GEMM
// 256x256 tile, BK=32, 8 waves (2M x 4N), per-wave 128x64 output.
// 3-deep LDS ring (96 KB): compute tile t from buf t%3, stage t+2 into (t+2)%3
// -> boundary wait is vmcnt(4) (tile t+1's loads ride through the barrier).
// Phase template per tile (2 phases): {ds_read frags || 2x global_load_lds ->
// s_barrier -> setprio(1) -> 16 MFMA -> setprio(0) -> s_barrier}.
// LDS swizzle: 64B rows, 16B chunk p = c ^ ((row>>1)&3); realized on the stage
// side by pre-swizzling the per-lane GLOBAL source (gload_lds dest is linear).
// Conflict check: every aligned 8-lane group of a ds_read_b128 hits 8 distinct
// 16B slots mod 128B -> conflict-free.
__global__ __launch_bounds__(512, 2)
void gemm_bf16(const u16* __restrict__ A, int lda,
               const u16* __restrict__ Bt,        // [N][K] bf16 (B^T)
               const float* __restrict__ bias,    // [N]
               const u16* __restrict__ addsrc, int ldadd,  // optional epilogue add
               u16* __restrict__ C, int ldc,
               int N, int K, int batch_rows) {    // batch_rows>0: Bt per-batch
    __shared__ u16 lds[3 * 16384];   // 96 KB: per buf A[256][32] + B[256][32]
    int ntiles = N >> 8;
    int bid = blockIdx.x;
    int mtiles = gridDim.x / ntiles;
    int tm, tn;
    if ((mtiles & 7) == 0) {
        int xcd = bid & 7, s = bid >> 3;
        int mper = mtiles >> 3;
        tm = xcd * mper + s / ntiles;
        tn = s - (s / ntiles) * ntiles;
    } else {
        tm = bid / ntiles; tn = bid - (bid / ntiles) * ntiles;
    }
    int m0 = tm << 8, n0 = tn << 8;
    if (batch_rows > 0) Bt += (size_t)(m0 / batch_rows) * (size_t)N * K;
    int tid = threadIdx.x, lane = tid & 63, w = tid >> 6;
    int wm = w >> 2, wn = w & 3;               // 2 M-warps x 4 N-warps
    int quad = lane >> 4, l16 = lane & 15;

    // ---- staging addressing (per-thread, swizzled global source) ----
    // wave w, issue j covers rows (w*2+j)*16 .. +15; lane l -> row +(l>>2),
    // physical chunk l&3, logical chunk (l&3)^((l>>3)&3).
    int srow = (w << 5) + (lane >> 2);
    int sk = ((lane & 3) ^ ((lane >> 3) & 3)) << 3;
    const u16* Asrc = A  + (size_t)(m0 + srow) * lda + sk;
    const u16* Bsrc = Bt + (size_t)(n0 + srow) * K   + sk;
    int ldst = w << 10;                        // (w*2)*512 u16, j adds 512
    int astep = lda << 4, bstep = K << 4;      // 16 rows of elements

    // ---- fragment read addressing ----
    int swz = (quad ^ ((l16 >> 1) & 3)) << 3;  // physical chunk * 8 u16
    int aoff = (((wm << 7) + l16) << 5) + swz;         // A rows wm*128+..
    int boff = (((wn << 6) + l16) << 5) + swz + 8192;  // B rows wn*64+..
    int nt = K >> 5;

    f32x4 zero = {0.f, 0.f, 0.f, 0.f};
    f32x4 acc[8][4];
    #pragma unroll
    for (int i = 0; i < 8; ++i)
        #pragma unroll
        for (int j = 0; j < 4; ++j) acc[i][j] = zero;

    // ---- prologue: stage tiles 0 and 1, wait for tile 0 (retain tile 1) ----
    GLD16(Asrc,                &lds[ldst]);
    GLD16(Asrc + astep,        &lds[ldst + 512]);
    GLD16(Bsrc,                &lds[8192 + ldst]);
    GLD16(Bsrc + bstep,        &lds[8192 + ldst + 512]);
    GLD16(Asrc + 32,           &lds[16384 + ldst]);
    GLD16(Asrc + astep + 32,   &lds[16384 + ldst + 512]);
    GLD16(Bsrc + 32,           &lds[16384 + 8192 + ldst]);
    GLD16(Bsrc + bstep + 32,   &lds[16384 + 8192 + ldst + 512]);
    asm volatile("s_waitcnt vmcnt(4)" ::: "memory");
    __builtin_amdgcn_s_barrier();

    int bufc = 0;
    int koff = 64;                              // element k-offset of tile t+2
    for (int t = 0; t < nt; ++t) {
        const u16* Lc = lds + (bufc << 14);
        int bufs = bufc + 2; if (bufs >= 3) bufs -= 3;
        u16* Ls = lds + (bufs << 14);
        bool pf = (t + 2 < nt);

        // ---- phase 0: B frags (held for both phases) + A frags mi 0..3 ----
        bf16x8 bfr[4], afr[4];
        #pragma unroll
        for (int ni = 0; ni < 4; ++ni)
            bfr[ni] = *(const bf16x8*)&Lc[boff + (ni << 9)];
        #pragma unroll
        for (int mi = 0; mi < 4; ++mi)
            afr[mi] = *(const bf16x8*)&Lc[aoff + (mi << 9)];
        if (pf) {
            GLD16(Asrc + koff,         &Ls[ldst]);
            GLD16(Asrc + astep + koff, &Ls[ldst + 512]);
        }
        asm volatile("" ::: "memory");
        __builtin_amdgcn_s_barrier();
        __builtin_amdgcn_s_setprio(1);
        #pragma unroll
        for (int mi = 0; mi < 4; ++mi)
            #pragma unroll
            for (int ni = 0; ni < 4; ++ni)
                acc[mi][ni] = __builtin_amdgcn_mfma_f32_16x16x32_bf16(
                    afr[mi], bfr[ni], acc[mi][ni], 0, 0, 0);
        __builtin_amdgcn_s_setprio(0);
        asm volatile("" ::: "memory");
        __builtin_amdgcn_s_barrier();

        // ---- phase 1: A frags mi 4..7 ----
        #pragma unroll
        for (int mi = 0; mi < 4; ++mi)
            afr[mi] = *(const bf16x8*)&Lc[aoff + ((mi + 4) << 9)];
        if (pf) {
            GLD16(Bsrc + koff,         &Ls[8192 + ldst]);
            GLD16(Bsrc + bstep + koff, &Ls[8192 + ldst + 512]);
        }
        asm volatile("" ::: "memory");
        __builtin_amdgcn_s_barrier();
        __builtin_amdgcn_s_setprio(1);
        #pragma unroll
        for (int mi = 0; mi < 4; ++mi)
            #pragma unroll
            for (int ni = 0; ni < 4; ++ni)
                acc[mi + 4][ni] = __builtin_amdgcn_mfma_f32_16x16x32_bf16(
                    afr[mi], bfr[ni], acc[mi + 4][ni], 0, 0, 0);
        __builtin_amdgcn_s_setprio(0);
        // boundary: need tile t+1 landed; keep tile t+2's 4 loads in flight
        if (pf) asm volatile("s_waitcnt vmcnt(4)" ::: "memory");
        else    asm volatile("s_waitcnt vmcnt(0)" ::: "memory");
        __builtin_amdgcn_s_barrier();

        koff += 32;
        bufc = (bufc == 2) ? 0 : bufc + 1;
    }

    // epilogue: C/D layout col=lane&15, row=quad*4+reg (verified m89/m91)
    #pragma unroll
    for (int mi = 0; mi < 8; ++mi) {
        #pragma unroll
        for (int ni = 0; ni < 4; ++ni) {
            int col = n0 + (wn << 6) + (ni << 4) + l16;
            float bv = bias[col];
            #pragma unroll
            for (int rg = 0; rg < 4; ++rg) {
                int rowg = m0 + (wm << 7) + (mi << 4) + (quad << 2) + rg;
                float vv = acc[mi][ni][rg] + bv;
                if (addsrc) vv += b2f(addsrc[(size_t)rowg * ldadd + col]);
                C[(size_t)rowg * ldc + col] = f2b(vv);
            }
        }
    }
}

// ------------------------------------------------- score GEMM ([Nrows]x[16])
// out[b][h][s] = 0.125*(dot(A_row, Bt[h]) + bias16[h]) + mask[b][s]
// 256 rows/block, BK=64, 8 MFMA per barrier pair, XOR-swizzled LDS.
__global__ __launch_bounds__(256)
void score_gemm(const u16* __restrict__ A, int lda,
                const u16* __restrict__ Bt,     // [16][1024] bf16 (per batch if batched)
                const float* __restrict__ bias16,
                const float* __restrict__ mask, // [8][4096]
                float* __restrict__ outsc,      // [8][16][4096]
                int batched) {
    __shared__ u16 As[256 * 64];   // 32 KB
    __shared__ u16 Bs[16 * 64];    //  2 KB
    int m0 = blockIdx.x << 8;      // 256 rows per block (within one batch: 4096%256==0)
    int tid = threadIdx.x, lane = tid & 63, w = tid >> 6;
    int quad = lane >> 4, l16 = lane & 15;
    int rph = l16 & 7;
    int lrow = lane >> 3;
    int lkg  = (lane & 7) ^ lrow;
    const u16* Bb = Bt + (batched ? ((size_t)(m0 >> 12) << 14) : 0);

    int idxA = (m0 + (w << 6) + lrow) * lda + (lkg << 3);  // chunk c=w*8+j rows
    int stepA = lda << 3;
    int idxB = lrow * 1024 + (lkg << 3);                    // rows h = c*8+lrow

    f32x4 acc4[4];
    #pragma unroll
    for (int i = 0; i < 4; ++i) acc4[i] = (f32x4){0.f, 0.f, 0.f, 0.f};

    for (int kt = 0; kt < 1024; kt += 64) {
        __syncthreads();
        #pragma unroll
        for (int j = 0; j < 8; ++j) {
            int c = (w << 3) + j;
            GLD16(A + (idxA + j * stepA + kt), &As[c << 9]);
        }
        if (w < 2)
            GLD16(Bb + (idxB + w * 8192 + kt), &Bs[w << 9]);
        __syncthreads();
        #pragma unroll
        for (int kk = 0; kk < 2; ++kk) {
            int kg = (((kk << 2) + quad) ^ rph) << 3;
            bf16x8 b = *(const bf16x8*)&Bs[(l16 << 6) + kg];
            #pragma unroll
            for (int mi = 0; mi < 4; ++mi) {
                bf16x8 a = *(const bf16x8*)&As[(((w << 6) + (mi << 4) + l16) << 6) + kg];
                acc4[mi] = __builtin_amdgcn_mfma_f32_16x16x32_bf16(a, b, acc4[mi], 0, 0, 0);
            }
        }
    }
    int bidx = m0 >> 12;
    float bv = bias16[l16];
    float* orow = outsc + (((size_t)bidx << 4) + l16) * 4096;
    const float* mrow = mask + ((size_t)bidx << 12);
    #pragma unroll
    for (int mi = 0; mi < 4; ++mi) {
        int sbase = (m0 & 4095) + (w << 6) + (mi << 4) + (quad << 2);
        #pragma unroll
        for (int rg = 0; rg < 4; ++rg)
            orow[sbase + rg] = 0.125f * (acc4[mi][rg] + bv) + mrow[sbase + rg];
    }
}

// ------------------------------------- softmax over S + weighted pool per (b,h)
__global__ __launch_bounds__(256)
void pool_kernel(const float* __restrict__ score,   // [8][16][4096]
                 const u16* __restrict__ X, int ldx, // q or k rows, bf16
                 const float* __restrict__ mulvec,   // null or q_av [8][1024]
                 float* __restrict__ outav) {        // [8][1024]
    __shared__ float wbuf[4096];
    __shared__ float red[4];
    __shared__ float psum[16][64];
    int b = blockIdx.x >> 4, h = blockIdx.x & 15;
    int tid = threadIdx.x, lane = tid & 63, w = tid >> 6;
    const float* srow = score + (((size_t)b << 4) + h) * 4096;
    float mx = -1e30f;
    for (int s = tid; s < 4096; s += 256) mx = fmaxf(mx, srow[s]);
    for (int o = 32; o; o >>= 1) mx = fmaxf(mx, __shfl_xor(mx, o));
    if (lane == 0) red[w] = mx;
    __syncthreads();
    mx = fmaxf(fmaxf(red[0], red[1]), fmaxf(red[2], red[3]));
    __syncthreads();
    float sm = 0.f;
    for (int s = tid; s < 4096; s += 256) {
        float e = __expf(srow[s] - mx);
        wbuf[s] = e;
        sm += e;
    }
    for (int o = 32; o; o >>= 1) sm += __shfl_xor(sm, o);
    if (lane == 0) red[w] = sm;
    __syncthreads();
    float inv = 1.f / (red[0] + red[1] + red[2] + red[3]);
    int dg = (tid & 15) << 2;   // 4 of 64 dims in head
    int sc = tid >> 4;          // 16 s-chunks of 256
    const u16* base = X + ((size_t)(b << 12)) * ldx + (h << 6) + dg;
    float a0 = 0, a1 = 0, a2 = 0, a3 = 0;
    for (int s = sc << 8; s < (sc << 8) + 256; ++s) {
        float wv = wbuf[s];
        ushort4 uv = *(const ushort4*)(base + (size_t)s * ldx);
        a0 += wv * b2f(uv.x); a1 += wv * b2f(uv.y);
        a2 += wv * b2f(uv.z); a3 += wv * b2f(uv.w);
    }
    psum[sc][dg + 0] = a0; psum[sc][dg + 1] = a1;
    psum[sc][dg + 2] = a2; psum[sc][dg + 3] = a3;
    __syncthreads();
    if (tid < 64) {
        float t = 0.f;
        #pragma unroll
        for (int j = 0; j < 16; ++j) t += psum[j][tid];
        t *= inv;
        if (mulvec) t *= mulvec[((size_t)b << 10) + (h << 6) + tid];
        outav[((size_t)b << 10) + (h << 6) + tid] = t;
    }
}

// ---------------------------------------------------------------- layernorm
__global__ __launch_bounds__(256)
void ln_kernel(const u16* __restrict__ Z, const float* __restrict__ g,
               const float* __restrict__ bta, float* __restrict__ outp) {
    __shared__ float rs1[4], rs2[4];
    int row = blockIdx.x, tid = threadIdx.x;
    const u16* zr = Z + ((size_t)row << 10);
    ushort4 uv = *(const ushort4*)(zr + (tid << 2));
    float v0 = b2f(uv.x), v1 = b2f(uv.y), v2 = b2f(uv.z), v3 = b2f(uv.w);
    float s = v0 + v1 + v2 + v3;
    float s2 = v0 * v0 + v1 * v1 + v2 * v2 + v3 * v3;
    for (int o = 32; o; o >>= 1) { s += __shfl_xor(s, o); s2 += __shfl_xor(s2, o); }
    if ((tid & 63) == 0) { rs1[tid >> 6] = s; rs2[tid >> 6] = s2; }
    __syncthreads();
    float S = rs1[0] + rs1[1] + rs1[2] + rs1[3];
    float S2 = rs2[0] + rs2[1] + rs2[2] + rs2[3];
    float mean = S * (1.0f / 1024.0f);
    float var = S2 * (1.0f / 1024.0f) - mean * mean;
    float inv = rsqrtf(var + 1e-6f);
    int c = tid << 2;
    float4 o4;
    o4.x = (v0 - mean) * inv * g[c + 0] + bta[c + 0];
    o4.y = (v1 - mean) * inv * g[c + 1] + bta[c + 1];
    o4.z = (v2 - mean) * inv * g[c + 2] + bta[c + 2];
    o4.w = (v3 - mean) * inv * g[c + 3] + bta[c + 3];
    *(float4*)(outp + ((size_t)row << 10) + c) = o4;
}

// ---------------------------------------------------------------- launch

extern "C" void kernel_launch(void* const* d_in, const int* in_sizes, int n_in,
                              void* d_out, int out_size, void* d_ws, size_t ws_size,
                              hipStream_t stream) {
    (void)in_sizes; (void)n_in; (void)out_size;
    const float* x    = (const float*)d_in[0];
    const float* mask = (const float*)d_in[1];
    const float* Wq   = (const float*)d_in[2];
    const float* bq   = (const float*)d_in[3];
    const float* Wk   = (const float*)d_in[4];
    const float* bk   = (const float*)d_in[5];
    const float* Wv   = (const float*)d_in[6];
    const float* bv   = (const float*)d_in[7];
    const float* Wa   = (const float*)d_in[8];
    const float* ba   = (const float*)d_in[9];
    const float* Wb   = (const float*)d_in[10];
    const float* bb   = (const float*)d_in[11];
    const float* Wu   = (const float*)d_in[12];
    const float* bu   = (const float*)d_in[13];
    const float* Wo   = (const float*)d_in[14];
    const float* bo   = (const float*)d_in[15];
    const float* ln_g = (const float*)d_in[16];
    const float* ln_b = (const float*)d_in[17];
    float* outp = (float*)d_out;

    char* ws = (char*)d_ws;
    // layout (bytes, all 256-aligned)
    u16*   xb    = (u16*)(ws);                     //  67,108,864  x bf16; later aliased by z
    u16*   qkv   = (u16*)(ws + 67108864);          // 201,326,592  [32768][3072]; q-region aliased by t
    u16*   Wqkvt = (u16*)(ws + 268435456);         //   6,291,456
    u16*   Wot   = (u16*)(ws + 274726912);         //   2,097,152
    u16*   Wat   = (u16*)(ws + 276824064);         //      32,768
    u16*   Wbt   = (u16*)(ws + 276856832);         //     262,144
    float* score = (float*)(ws + 277118976);       //   2,097,152 (reused for a & b scores)
    float* q_av  = (float*)(ws + 279216128);       //      32,768
    float* p_av  = (float*)(ws + 279248896);       //      32,768
    float* biasq = (float*)(ws + 279281664);       //      12,288
    u16*   Wubt  = (u16*)(ws + 279293952);         //  16,777,216  -> total 296,071,168
    if (ws_size < 296071168ULL) return;

    convert_x<<<16384, 256, 0, stream>>>(x, xb);
    transpose_w<<<256, 256, 0, stream>>>(Wq, Wqkvt);
    transpose_w<<<256, 256, 0, stream>>>(Wk, Wqkvt + 1048576);
    transpose_w<<<256, 256, 0, stream>>>(Wv, Wqkvt + 2097152);
    transpose_w<<<256, 256, 0, stream>>>(Wo, Wot);
    wat_prep<<<64, 256, 0, stream>>>(Wa, Wat);
    bias_concat<<<12, 256, 0, stream>>>(bq, bk, bv, biasq);

    // qkv = x @ [Wq|Wk|Wv] + bias   (M=32768, N=3072, K=1024), 256x256 tiles
    gemm_bf16<<<1536, 512, 0, stream>>>(xb, 1024, Wqkvt, biasq,
                                        nullptr, 0, qkv, 3072, 3072, 1024, 0);
    // ascore
    score_gemm<<<128, 256, 0, stream>>>(qkv, 3072, Wat, ba, mask, score, 0);
    // alpha softmax+pool -> q_av
    pool_kernel<<<128, 256, 0, stream>>>(score, qkv, 3072, nullptr, q_av);
    // per-batch Wb' = diag(q_av) Wb
    wbt_prep<<<512, 256, 0, stream>>>(Wb, q_av, Wbt);
    // bscore = k @ Wb'
    score_gemm<<<128, 256, 0, stream>>>(qkv + 1024, 3072, Wbt, bb, mask, score, 1);
    // beta softmax+pool, times q_av -> p_av
    pool_kernel<<<128, 256, 0, stream>>>(score, qkv + 1024, 3072, q_av, p_av);
    // per-batch Wu' = diag(p_av) Wu (transposed, bf16)
    wu_prime<<<256, 256, 0, stream>>>(Wu, p_av, Wubt);
    // t = v @ Wu'_b + bu + q   (writes over q region; element read-before-write)
    gemm_bf16<<<512, 512, 0, stream>>>(qkv + 2048, 3072, Wubt, bu,
                                       qkv, 3072, qkv, 3072, 1024, 1024, 4096);
    // z = t @ Wo^T + bo + x    (writes over xb; element read-before-write)
    gemm_bf16<<<512, 512, 0, stream>>>(qkv, 3072, Wot, bo,
                                       xb, 1024, xb, 1024, 1024, 1024, 0);
    // layernorm -> out (f32)
    ln_kernel<<<32768, 256, 0, stream>>>(xb, ln_g, ln_b, outp);
}